// Round 1
// baseline (155.338 us; speedup 1.0000x reference)
//
#include <hip/hip_runtime.h>
#include <hip/hip_bf16.h>
#include <math.h>

#define D_DIM   4096
#define B_ROWS  4096
#define K_CODES 256
#define MARGIN  3.0      // |approx d2 - exact d2| <= ~1.5 worst-case; 3.0 window
#define KS      4        // K-split
#define KSLICE  (D_DIM / KS)   // 1024
#define BK      64             // 16 iters per block
#define NITER   (KSLICE / BK)

// output layout (f32 elements)
#define IDX_OFF   (B_ROWS * D_DIM)                 // 16777216
#define PROBS_OFF (IDX_OFF + B_ROWS)               // 16781312
#define LOSS_OFF  (PROBS_OFF + B_ROWS * K_CODES)   // 17829888

typedef __bf16 bf16x8 __attribute__((ext_vector_type(8)));
typedef float  f32x16 __attribute__((ext_vector_type(16)));

// ws: part[KS][4096][256] f32 (16 MB) | cbh_sw (2 MB) | cc[256] f64 | xxp[KS][4096] f32
// cbh_sw layout: [panel = k/64][q = (k/8)&7][code][off = k&7] ushort
#define PART_ELEMS ((size_t)KS * B_ROWS * K_CODES)

static __device__ inline unsigned short f2bf(float f) {
    __hip_bfloat16 h = __float2bfloat16(f);
    return *reinterpret_cast<unsigned short*>(&h);
}

// ---------------------------------------------------------------------------
// prep_cb: wave-per-codebook-row. Writes swizzled bf16 codebook + cc (f64).
// ---------------------------------------------------------------------------
__global__ __launch_bounds__(256) void prep_cb(const float* __restrict__ cb,
                                               unsigned short* __restrict__ cbsw,
                                               double* __restrict__ cc) {
    const int lane = threadIdx.x & 63;
    const int k = blockIdx.x * 4 + (threadIdx.x >> 6);   // code 0..255
    const float4* row4 = (const float4*)(cb + (size_t)k * D_DIM);
    double a0 = 0.0, a1 = 0.0, a2 = 0.0, a3 = 0.0;
#pragma unroll
    for (int i = 0; i < 16; ++i) {
        float4 v = row4[i * 64 + lane];
        a0 += (double)v.x * v.x; a1 += (double)v.y * v.y;
        a2 += (double)v.z * v.z; a3 += (double)v.w * v.w;
        ushort4 h;
        h.x = f2bf(v.x); h.y = f2bf(v.y); h.z = f2bf(v.z); h.w = f2bf(v.w);
        const int c = (i * 64 + lane) * 4;           // global k of this chunk
        const int panel = c >> 6, q = (c >> 3) & 7, off = c & 7;
        *(ushort4*)&cbsw[(((size_t)panel * 8 + q) * K_CODES + k) * 8 + off] = h;
    }
    double s = (a0 + a1) + (a2 + a3);
    for (int off = 32; off; off >>= 1) s += __shfl_xor(s, off);
    if (lane == 0) cc[k] = s;
}

// ---------------------------------------------------------------------------
// gemm: block = 32 rows x 256 codes x KSLICE, grid (128, KS), 4 blocks/CU.
// B: swizzled bf16 codebook DMA'd linearly (fully coalesced) -> LDS layout
//    [q][code][8] -> frag reads lane-contiguous (conflict-free).
// A: coalesced f32 loads (128B per 8 lanes) -> bf16 -> LDS in frag order
//    [q][row][8] -> frag reads lane-contiguous. xx partials fused (f32).
// ---------------------------------------------------------------------------
__global__ __launch_bounds__(256, 4) void gemm(const float* __restrict__ x,
                                               const unsigned short* __restrict__ cbsw,
                                               float* __restrict__ part,
                                               float* __restrict__ xxp) {
    __shared__ unsigned short As[8 * 32 * 8];        // [q][row][8]  4 KB
    __shared__ unsigned short Bs[8 * K_CODES * 8];   // [q][code][8] 32 KB
    const int t = threadIdx.x;
    const int lane = t & 63, w = t >> 6;
    const int h = lane >> 5, mr = lane & 31;
    const int m0 = blockIdx.x * 32;
    const int ks = blockIdx.y;
    const int k0 = ks * KSLICE;

    // A staging: thread t -> row t>>3, cols 4*(t&7) and 4*(t&7)+32 of each BK tile
    const int arow = t >> 3, acg = 4 * (t & 7);
    const float* ag = x + (size_t)(m0 + arow) * D_DIM + k0 + acg;
    unsigned short* aw0 = &As[(((acg >> 3)    ) * 32 + arow) * 8 + (acg & 7)];
    unsigned short* aw1 = &As[(((acg >> 3) + 4) * 32 + arow) * 8 + (acg & 7)];
    // B DMA: linear in cbsw; per-iter stride = 64 k * 256 codes = 16384 ushort
    const unsigned short* bg = cbsw + (size_t)(ks * NITER) * 16384 + t * 8;

    f32x16 acc0, acc1;
#pragma unroll
    for (int i = 0; i < 16; ++i) { acc0[i] = 0.f; acc1[i] = 0.f; }
    float sq = 0.f;

    float4 a0 = *(const float4*)(ag);
    float4 a1 = *(const float4*)(ag + 32);
    for (int it = 0; it < NITER; ++it) {
        const int kn = (it + 1 < NITER) ? (it + 1) * BK : 0;   // clamped, valid
        float4 n0 = *(const float4*)(ag + kn);
        float4 n1 = *(const float4*)(ag + kn + 32);
        __syncthreads();   // previous iter's LDS frag reads complete
#pragma unroll
        for (int r = 0; r < 8; ++r)
            __builtin_amdgcn_global_load_lds(
                (const __attribute__((address_space(1))) void*)(bg + (size_t)it * 16384 + r * 2048),
                (__attribute__((address_space(3))) void*)(&Bs[(t + 256 * r) * 8]),
                16, 0, 0);
        ushort4 h0, h1;
        h0.x = f2bf(a0.x); h0.y = f2bf(a0.y); h0.z = f2bf(a0.z); h0.w = f2bf(a0.w);
        h1.x = f2bf(a1.x); h1.y = f2bf(a1.y); h1.z = f2bf(a1.z); h1.w = f2bf(a1.w);
        *(ushort4*)aw0 = h0;
        *(ushort4*)aw1 = h1;
        sq += a0.x*a0.x + a0.y*a0.y + a0.z*a0.z + a0.w*a0.w
            + a1.x*a1.x + a1.y*a1.y + a1.z*a1.z + a1.w*a1.w;
        __syncthreads();   // drains ds_write + DMA before frag reads
#pragma unroll
        for (int s = 0; s < 4; ++s) {
            const int q = 2 * s + h;
            bf16x8 af = *(const bf16x8*)&As[(q * 32 + mr) * 8];
            bf16x8 b0 = *(const bf16x8*)&Bs[(q * K_CODES + w * 64 + mr) * 8];
            bf16x8 b1 = *(const bf16x8*)&Bs[(q * K_CODES + w * 64 + 32 + mr) * 8];
            acc0 = __builtin_amdgcn_mfma_f32_32x32x16_bf16(af, b0, acc0, 0, 0, 0);
            acc1 = __builtin_amdgcn_mfma_f32_32x32x16_bf16(af, b1, acc1, 0, 0, 0);
        }
        a0 = n0; a1 = n1;
    }

    // xx partials: reduce sq over the 8 threads sharing a row (lanes t&7)
    sq += __shfl_xor(sq, 1);
    sq += __shfl_xor(sq, 2);
    sq += __shfl_xor(sq, 4);
    if ((t & 7) == 0) xxp[(size_t)ks * B_ROWS + m0 + arow] = sq;

    float* dst = part + ((size_t)ks * B_ROWS + m0) * K_CODES + w * 64;
#pragma unroll
    for (int r = 0; r < 16; ++r) {
        const int rowit = (r & 3) + 8 * (r >> 2) + 4 * h;
        dst[(size_t)rowit * K_CODES + mr]      = acc0[r];
        dst[(size_t)rowit * K_CODES + 32 + mr] = acc1[r];
    }
}

// ---------------------------------------------------------------------------
// finish: wave-per-row. d2 from partials (f64), butterfly max, margin
// candidates; single candidate -> done; else exact f64 refinement (rare).
// Writes idx, loss, probs(=0), quant row. No LDS, no barriers.
// ---------------------------------------------------------------------------
__global__ __launch_bounds__(256) void finish(const float* __restrict__ x,
                                              const float* __restrict__ cb,
                                              const float* __restrict__ part,
                                              const double* __restrict__ cc,
                                              const float* __restrict__ xxp,
                                              float* __restrict__ out) {
    const int lane = threadIdx.x & 63;
    const int row = blockIdx.x * 4 + (threadIdx.x >> 6);

    double xx = ((double)xxp[row] + (double)xxp[B_ROWS + row])
              + ((double)xxp[2 * B_ROWS + row] + (double)xxp[3 * B_ROWS + row]);
    float4 p[KS];
#pragma unroll
    for (int s = 0; s < KS; ++s)
        p[s] = ((const float4*)(part + ((size_t)s * B_ROWS + row) * K_CODES))[lane];
    double v[4];
    v[0] = xx + cc[4 * lane + 0] - 2.0 * (((double)p[0].x + p[1].x) + ((double)p[2].x + p[3].x));
    v[1] = xx + cc[4 * lane + 1] - 2.0 * (((double)p[0].y + p[1].y) + ((double)p[2].y + p[3].y));
    v[2] = xx + cc[4 * lane + 2] - 2.0 * (((double)p[0].z + p[1].z) + ((double)p[2].z + p[3].z));
    v[3] = xx + cc[4 * lane + 3] - 2.0 * (((double)p[0].w + p[1].w) + ((double)p[2].w + p[3].w));

    double mx = fmax(fmax(v[0], v[1]), fmax(v[2], v[3]));
    for (int off = 32; off; off >>= 1) mx = fmax(mx, __shfl_xor(mx, off));
    const double thr = mx - MARGIN;

    unsigned long long b[4];
#pragma unroll
    for (int j = 0; j < 4; ++j) b[j] = __ballot(v[j] >= thr);
    const int total = __popcll(b[0]) + __popcll(b[1]) + __popcll(b[2]) + __popcll(b[3]);

    int bestk = 0; double best;
    if (total == 1) {
        best = mx;   // lone candidate IS the max; error bound guarantees argmax
#pragma unroll
        for (int j = 0; j < 4; ++j)
            if (b[j]) bestk = 4 * (int)__builtin_ctzll(b[j]) + j;
    } else {
        const float4* xrow4 = (const float4*)(x + (size_t)row * D_DIM);
        int flags = 0;
#pragma unroll
        for (int j = 0; j < 4; ++j) if (v[j] >= thr) flags |= 1 << j;
        unsigned long long cand = __ballot(flags != 0);
        best = -1.0e300;
        while (cand) {
            const int lsrc = __builtin_ctzll(cand);
            cand &= cand - 1;
            const int f = __shfl(flags, lsrc);
            for (int j = 0; j < 4; ++j) {
                if (!((f >> j) & 1)) continue;
                const int k = 4 * lsrc + j;
                const float4* crow4 = (const float4*)(cb + (size_t)k * D_DIM);
                double a0 = 0.0, a1 = 0.0, a2 = 0.0, a3 = 0.0;
#pragma unroll
                for (int i = 0; i < 16; ++i) {
                    float4 xa = xrow4[i * 64 + lane];
                    float4 ca = crow4[i * 64 + lane];
                    a0 += (double)xa.x * ca.x; a1 += (double)xa.y * ca.y;
                    a2 += (double)xa.z * ca.z; a3 += (double)xa.w * ca.w;
                }
                double s = (a0 + a1) + (a2 + a3);
                for (int off = 32; off; off >>= 1) s += __shfl_xor(s, off);
                const double d2e = xx + cc[k] - 2.0 * s;    // identical across lanes
                if (d2e > best) { best = d2e; bestk = k; }  // ascending k, strict >
            }
        }
    }

    if (lane == 0) {
        out[IDX_OFF + row]  = (float)bestk;
        out[LOSS_OFF + row] = (float)(1.25 * best / (double)D_DIM);
    }
    float4 z = make_float4(0.f, 0.f, 0.f, 0.f);
    ((float4*)(out + PROBS_OFF + (size_t)row * K_CODES))[lane] = z;
    const float4* src = (const float4*)(cb + (size_t)bestk * D_DIM);
    float4* dst = (float4*)(out + (size_t)row * D_DIM);
#pragma unroll
    for (int i = 0; i < 16; ++i) dst[i * 64 + lane] = src[i * 64 + lane];
}

// ---------------------------------------------------------------------------
extern "C" void kernel_launch(void* const* d_in, const int* in_sizes, int n_in,
                              void* d_out, int out_size, void* d_ws, size_t ws_size,
                              hipStream_t stream) {
    const float* x  = (const float*)d_in[0];
    const float* cb = (const float*)d_in[1];
    float* out = (float*)d_out;

    float*          part = (float*)d_ws;
    unsigned short* cbsw = (unsigned short*)((char*)d_ws + PART_ELEMS * sizeof(float));
    double*         cc   = (double*)((char*)cbsw + (size_t)K_CODES * D_DIM * sizeof(unsigned short));
    float*          xxp  = (float*)(cc + K_CODES);

    hipLaunchKernelGGL(prep_cb, dim3(64),      dim3(256), 0, stream, cb, cbsw, cc);
    hipLaunchKernelGGL(gemm,    dim3(128, KS), dim3(256), 0, stream, x, cbsw, part, xxp);
    hipLaunchKernelGGL(finish,  dim3(1024),    dim3(256), 0, stream, x, cb, part, cc, xxp, out);
}

// Round 2
// 151.684 us; speedup vs baseline: 1.0241x; 1.0241x over previous
//
#include <hip/hip_runtime.h>
#include <hip/hip_bf16.h>
#include <math.h>

#define D_DIM   4096
#define B_ROWS  4096
#define K_CODES 256
#define MARGIN  3.0      // |approx d2 - exact d2| <= ~1.5 worst-case; 3.0 window
#define KS      4        // K-split
#define KSLICE  (D_DIM / KS)   // 1024
#define BK      64             // 16 iters per block
#define NITER   (KSLICE / BK)

// output layout (f32 elements)
#define IDX_OFF   (B_ROWS * D_DIM)                 // 16777216
#define PROBS_OFF (IDX_OFF + B_ROWS)               // 16781312
#define LOSS_OFF  (PROBS_OFF + B_ROWS * K_CODES)   // 17829888

typedef __bf16 bf16x8 __attribute__((ext_vector_type(8)));
typedef float  f32x16 __attribute__((ext_vector_type(16)));

// ws: part[KS][4096][256] f32 (16 MB) | cbh_sw (2 MB) | cc[256] f64 | xxp[KS][4096] f32
// cbh_sw layout: [panel = k/64][q = (k/8)&7][code][off = k&7] ushort
#define PART_ELEMS ((size_t)KS * B_ROWS * K_CODES)

static __device__ inline unsigned short f2bf(float f) {
    __hip_bfloat16 h = __float2bfloat16(f);
    return *reinterpret_cast<unsigned short*>(&h);
}

// ---------------------------------------------------------------------------
// prep_cb: wave-per-codebook-row. Writes swizzled bf16 codebook + cc (f64).
// ---------------------------------------------------------------------------
__global__ __launch_bounds__(256) void prep_cb(const float* __restrict__ cb,
                                               unsigned short* __restrict__ cbsw,
                                               double* __restrict__ cc) {
    const int lane = threadIdx.x & 63;
    const int k = blockIdx.x * 4 + (threadIdx.x >> 6);   // code 0..255
    const float4* row4 = (const float4*)(cb + (size_t)k * D_DIM);
    double a0 = 0.0, a1 = 0.0, a2 = 0.0, a3 = 0.0;
#pragma unroll
    for (int i = 0; i < 16; ++i) {
        float4 v = row4[i * 64 + lane];
        a0 += (double)v.x * v.x; a1 += (double)v.y * v.y;
        a2 += (double)v.z * v.z; a3 += (double)v.w * v.w;
        ushort4 h;
        h.x = f2bf(v.x); h.y = f2bf(v.y); h.z = f2bf(v.z); h.w = f2bf(v.w);
        const int c = (i * 64 + lane) * 4;           // global k of this chunk
        const int panel = c >> 6, q = (c >> 3) & 7, off = c & 7;
        *(ushort4*)&cbsw[(((size_t)panel * 8 + q) * K_CODES + k) * 8 + off] = h;
    }
    double s = (a0 + a1) + (a2 + a3);
    for (int off = 32; off; off >>= 1) s += __shfl_xor(s, off);
    if (lane == 0) cc[k] = s;
}

// ---------------------------------------------------------------------------
// gemm v2: pipelined. Double-buffered As/Bs (72 KB LDS, 2 blocks/CU).
// Per iter: issue B DMA(t+1) -> cvt/write A(t+1) -> issue A(t+2) prefetch ->
// MFMA(t) -> s_waitcnt vmcnt(2) lgkmcnt(0) -> s_barrier.
// Issue order per iter is [B x8][A x2], so vmcnt(2) exactly drains the B DMAs
// needed at the next iter while keeping the newest A prefetch in flight.
// ---------------------------------------------------------------------------
__global__ __launch_bounds__(256, 2) void gemm(const float* __restrict__ x,
                                               const unsigned short* __restrict__ cbsw,
                                               float* __restrict__ part,
                                               float* __restrict__ xxp) {
    __shared__ unsigned short As[2][8 * 32 * 8];        // [p][q][row][8]   2 x 4 KB
    __shared__ unsigned short Bs[2][8 * K_CODES * 8];   // [p][q][code][8]  2 x 32 KB
    const int t = threadIdx.x;
    const int lane = t & 63, w = t >> 6;
    const int h = lane >> 5, mr = lane & 31;
    const int m0 = blockIdx.x * 32;
    const int ks = blockIdx.y;
    const int k0 = ks * KSLICE;

    // A staging: thread t -> row t>>3, cols 4*(t&7) and 4*(t&7)+32 of each BK tile
    const int arow = t >> 3, acg = 4 * (t & 7);
    const float* ag = x + (size_t)(m0 + arow) * D_DIM + k0 + acg;
    const int aw0 = (((acg >> 3)    ) * 32 + arow) * 8 + (acg & 7);
    const int aw1 = (((acg >> 3) + 4) * 32 + arow) * 8 + (acg & 7);
    // B DMA: linear in cbsw; per-iter stride = 64 k * 256 codes = 16384 ushort
    const unsigned short* bg = cbsw + (size_t)(ks * NITER) * 16384 + t * 8;

    f32x16 acc0, acc1;
#pragma unroll
    for (int i = 0; i < 16; ++i) { acc0[i] = 0.f; acc1[i] = 0.f; }
    float sq = 0.f;

    // ---- prologue: stage tile 0, prefetch A(1) ----
#pragma unroll
    for (int r = 0; r < 8; ++r)
        __builtin_amdgcn_global_load_lds(
            (const __attribute__((address_space(1))) void*)(bg + r * 2048),
            (__attribute__((address_space(3))) void*)(&Bs[0][(t + 256 * r) * 8]),
            16, 0, 0);
    float4 p0 = *(const float4*)(ag);            // A(0)
    float4 p1 = *(const float4*)(ag + 32);
    float4 n0 = *(const float4*)(ag + BK);       // A(1)
    float4 n1 = *(const float4*)(ag + BK + 32);
    {
        ushort4 h0, h1;
        h0.x = f2bf(p0.x); h0.y = f2bf(p0.y); h0.z = f2bf(p0.z); h0.w = f2bf(p0.w);
        h1.x = f2bf(p1.x); h1.y = f2bf(p1.y); h1.z = f2bf(p1.z); h1.w = f2bf(p1.w);
        *(ushort4*)&As[0][aw0] = h0;
        *(ushort4*)&As[0][aw1] = h1;
        sq += p0.x*p0.x + p0.y*p0.y + p0.z*p0.z + p0.w*p0.w
            + p1.x*p1.x + p1.y*p1.y + p1.z*p1.z + p1.w*p1.w;
    }
    asm volatile("s_waitcnt vmcnt(2) lgkmcnt(0)" ::: "memory");
    __builtin_amdgcn_s_barrier();
    __builtin_amdgcn_sched_barrier(0);

    // ---- main loop ----
#pragma unroll
    for (int it = 0; it < NITER; ++it) {
        const int p = it & 1, pn = p ^ 1;

        // phase A: stage tile it+1 into buffer pn
        if (it + 1 < NITER) {
#pragma unroll
            for (int r = 0; r < 8; ++r)
                __builtin_amdgcn_global_load_lds(
                    (const __attribute__((address_space(1))) void*)(bg + (size_t)(it + 1) * 16384 + r * 2048),
                    (__attribute__((address_space(3))) void*)(&Bs[pn][(t + 256 * r) * 8]),
                    16, 0, 0);
            ushort4 h0, h1;
            h0.x = f2bf(n0.x); h0.y = f2bf(n0.y); h0.z = f2bf(n0.z); h0.w = f2bf(n0.w);
            h1.x = f2bf(n1.x); h1.y = f2bf(n1.y); h1.z = f2bf(n1.z); h1.w = f2bf(n1.w);
            *(ushort4*)&As[pn][aw0] = h0;
            *(ushort4*)&As[pn][aw1] = h1;
            sq += n0.x*n0.x + n0.y*n0.y + n0.z*n0.z + n0.w*n0.w
                + n1.x*n1.x + n1.y*n1.y + n1.z*n1.z + n1.w*n1.w;
        }
        // phase A2: issue A(it+2) prefetch (clamped, always 2 loads -> stable vmcnt count)
        const int t2 = (it + 2 < NITER) ? (it + 2) * BK : 0;
        float4 m0v = *(const float4*)(ag + t2);
        float4 m1v = *(const float4*)(ag + t2 + 32);

        // phase B: MFMA on tile it (buffer p)
#pragma unroll
        for (int s = 0; s < 4; ++s) {
            const int q = 2 * s + h;
            bf16x8 af = *(const bf16x8*)&As[p][(q * 32 + mr) * 8];
            bf16x8 b0 = *(const bf16x8*)&Bs[p][(q * K_CODES + w * 64 + mr) * 8];
            bf16x8 b1 = *(const bf16x8*)&Bs[p][(q * K_CODES + w * 64 + 32 + mr) * 8];
            acc0 = __builtin_amdgcn_mfma_f32_32x32x16_bf16(af, b0, acc0, 0, 0, 0);
            acc1 = __builtin_amdgcn_mfma_f32_32x32x16_bf16(af, b1, acc1, 0, 0, 0);
        }

        // phase C: counted drain + barrier (publishes buffer pn for iter it+1)
        asm volatile("s_waitcnt vmcnt(2) lgkmcnt(0)" ::: "memory");
        __builtin_amdgcn_s_barrier();
        __builtin_amdgcn_sched_barrier(0);

        n0 = m0v; n1 = m1v;   // rotate A pipeline (SSA renames under full unroll)
    }

    // xx partials: reduce sq over the 8 threads sharing a row (lanes t&7)
    sq += __shfl_xor(sq, 1);
    sq += __shfl_xor(sq, 2);
    sq += __shfl_xor(sq, 4);
    if ((t & 7) == 0) xxp[(size_t)ks * B_ROWS + m0 + arow] = sq;

    float* dst = part + ((size_t)ks * B_ROWS + m0) * K_CODES + w * 64;
#pragma unroll
    for (int r = 0; r < 16; ++r) {
        const int rowit = (r & 3) + 8 * (r >> 2) + 4 * h;
        dst[(size_t)rowit * K_CODES + mr]      = acc0[r];
        dst[(size_t)rowit * K_CODES + 32 + mr] = acc1[r];
    }
}

// ---------------------------------------------------------------------------
// finish: wave-per-row. d2 from partials (f64), butterfly max, margin
// candidates; single candidate -> done; else exact f64 refinement (rare).
// Writes idx, loss, probs(=0), quant row. No LDS, no barriers.
// ---------------------------------------------------------------------------
__global__ __launch_bounds__(256) void finish(const float* __restrict__ x,
                                              const float* __restrict__ cb,
                                              const float* __restrict__ part,
                                              const double* __restrict__ cc,
                                              const float* __restrict__ xxp,
                                              float* __restrict__ out) {
    const int lane = threadIdx.x & 63;
    const int row = blockIdx.x * 4 + (threadIdx.x >> 6);

    double xx = ((double)xxp[row] + (double)xxp[B_ROWS + row])
              + ((double)xxp[2 * B_ROWS + row] + (double)xxp[3 * B_ROWS + row]);
    float4 p[KS];
#pragma unroll
    for (int s = 0; s < KS; ++s)
        p[s] = ((const float4*)(part + ((size_t)s * B_ROWS + row) * K_CODES))[lane];
    double v[4];
    v[0] = xx + cc[4 * lane + 0] - 2.0 * (((double)p[0].x + p[1].x) + ((double)p[2].x + p[3].x));
    v[1] = xx + cc[4 * lane + 1] - 2.0 * (((double)p[0].y + p[1].y) + ((double)p[2].y + p[3].y));
    v[2] = xx + cc[4 * lane + 2] - 2.0 * (((double)p[0].z + p[1].z) + ((double)p[2].z + p[3].z));
    v[3] = xx + cc[4 * lane + 3] - 2.0 * (((double)p[0].w + p[1].w) + ((double)p[2].w + p[3].w));

    double mx = fmax(fmax(v[0], v[1]), fmax(v[2], v[3]));
    for (int off = 32; off; off >>= 1) mx = fmax(mx, __shfl_xor(mx, off));
    const double thr = mx - MARGIN;

    unsigned long long b[4];
#pragma unroll
    for (int j = 0; j < 4; ++j) b[j] = __ballot(v[j] >= thr);
    const int total = __popcll(b[0]) + __popcll(b[1]) + __popcll(b[2]) + __popcll(b[3]);

    int bestk = 0; double best;
    if (total == 1) {
        best = mx;   // lone candidate IS the max; error bound guarantees argmax
#pragma unroll
        for (int j = 0; j < 4; ++j)
            if (b[j]) bestk = 4 * (int)__builtin_ctzll(b[j]) + j;
    } else {
        const float4* xrow4 = (const float4*)(x + (size_t)row * D_DIM);
        int flags = 0;
#pragma unroll
        for (int j = 0; j < 4; ++j) if (v[j] >= thr) flags |= 1 << j;
        unsigned long long cand = __ballot(flags != 0);
        best = -1.0e300;
        while (cand) {
            const int lsrc = __builtin_ctzll(cand);
            cand &= cand - 1;
            const int f = __shfl(flags, lsrc);
            for (int j = 0; j < 4; ++j) {
                if (!((f >> j) & 1)) continue;
                const int k = 4 * lsrc + j;
                const float4* crow4 = (const float4*)(cb + (size_t)k * D_DIM);
                double a0 = 0.0, a1 = 0.0, a2 = 0.0, a3 = 0.0;
#pragma unroll
                for (int i = 0; i < 16; ++i) {
                    float4 xa = xrow4[i * 64 + lane];
                    float4 ca = crow4[i * 64 + lane];
                    a0 += (double)xa.x * ca.x; a1 += (double)xa.y * ca.y;
                    a2 += (double)xa.z * ca.z; a3 += (double)xa.w * ca.w;
                }
                double s = (a0 + a1) + (a2 + a3);
                for (int off = 32; off; off >>= 1) s += __shfl_xor(s, off);
                const double d2e = xx + cc[k] - 2.0 * s;    // identical across lanes
                if (d2e > best) { best = d2e; bestk = k; }  // ascending k, strict >
            }
        }
    }

    if (lane == 0) {
        out[IDX_OFF + row]  = (float)bestk;
        out[LOSS_OFF + row] = (float)(1.25 * best / (double)D_DIM);
    }
    float4 z = make_float4(0.f, 0.f, 0.f, 0.f);
    ((float4*)(out + PROBS_OFF + (size_t)row * K_CODES))[lane] = z;
    const float4* src = (const float4*)(cb + (size_t)bestk * D_DIM);
    float4* dst = (float4*)(out + (size_t)row * D_DIM);
#pragma unroll
    for (int i = 0; i < 16; ++i) dst[i * 64 + lane] = src[i * 64 + lane];
}

// ---------------------------------------------------------------------------
extern "C" void kernel_launch(void* const* d_in, const int* in_sizes, int n_in,
                              void* d_out, int out_size, void* d_ws, size_t ws_size,
                              hipStream_t stream) {
    const float* x  = (const float*)d_in[0];
    const float* cb = (const float*)d_in[1];
    float* out = (float*)d_out;

    float*          part = (float*)d_ws;
    unsigned short* cbsw = (unsigned short*)((char*)d_ws + PART_ELEMS * sizeof(float));
    double*         cc   = (double*)((char*)cbsw + (size_t)K_CODES * D_DIM * sizeof(unsigned short));
    float*          xxp  = (float*)(cc + K_CODES);

    hipLaunchKernelGGL(prep_cb, dim3(64),      dim3(256), 0, stream, cb, cbsw, cc);
    hipLaunchKernelGGL(gemm,    dim3(128, KS), dim3(256), 0, stream, x, cbsw, part, xxp);
    hipLaunchKernelGGL(finish,  dim3(1024),    dim3(256), 0, stream, x, cb, part, cc, xxp, out);
}

// Round 4
// 147.458 us; speedup vs baseline: 1.0534x; 1.0287x over previous
//
#include <hip/hip_runtime.h>
#include <hip/hip_bf16.h>
#include <math.h>

#define D_DIM   4096
#define B_ROWS  4096
#define K_CODES 256
#define MARGIN  3.0      // |approx d2 - exact d2| <= ~1.5 worst-case; 3.0 window
#define KS      8        // K-split
#define KSLICE  (D_DIM / KS)   // 512
#define BK      64
#define NITER   (KSLICE / BK)  // 8
#define MT      64             // M rows per block

// output layout (f32 elements)
#define IDX_OFF   (B_ROWS * D_DIM)                 // 16777216
#define PROBS_OFF (IDX_OFF + B_ROWS)               // 16781312
#define LOSS_OFF  (PROBS_OFF + B_ROWS * K_CODES)   // 17829888

typedef __bf16 bf16x8 __attribute__((ext_vector_type(8)));
typedef float  f32x16 __attribute__((ext_vector_type(16)));

// ws: part[KS][4096][256] f32 (32 MB) | cbsw (2 MB) | cc[256] f64 | xxp[KS][4096] f32
// cbsw layout: [panel = k/64][q = (k/8)&7][code][off = k&7] ushort
#define PART_ELEMS ((size_t)KS * B_ROWS * K_CODES)

static __device__ inline unsigned short f2bf(float f) {
    __hip_bfloat16 h = __float2bfloat16(f);
    return *reinterpret_cast<unsigned short*>(&h);
}

// ---------------------------------------------------------------------------
// prep_cb: one wave per codebook row, 256 blocks (4x CU coverage vs before).
// Writes swizzled bf16 codebook + cc (f64).
// ---------------------------------------------------------------------------
__global__ __launch_bounds__(64) void prep_cb(const float* __restrict__ cb,
                                              unsigned short* __restrict__ cbsw,
                                              double* __restrict__ cc) {
    const int lane = threadIdx.x & 63;
    const int k = blockIdx.x;                            // code 0..255
    const float4* row4 = (const float4*)(cb + (size_t)k * D_DIM);
    double a0 = 0.0, a1 = 0.0, a2 = 0.0, a3 = 0.0;
#pragma unroll
    for (int i = 0; i < 16; ++i) {
        float4 v = row4[i * 64 + lane];
        a0 += (double)v.x * v.x; a1 += (double)v.y * v.y;
        a2 += (double)v.z * v.z; a3 += (double)v.w * v.w;
        ushort4 h;
        h.x = f2bf(v.x); h.y = f2bf(v.y); h.z = f2bf(v.z); h.w = f2bf(v.w);
        const int c = (i * 64 + lane) * 4;           // global k of this chunk
        const int panel = c >> 6, q = (c >> 3) & 7, off = c & 7;
        *(ushort4*)&cbsw[(((size_t)panel * 8 + q) * K_CODES + k) * 8 + off] = h;
    }
    double s = (a0 + a1) + (a2 + a3);
    for (int off = 32; off; off >>= 1) s += __shfl_xor(s, off);
    if (lane == 0) cc[k] = s;
}

// ---------------------------------------------------------------------------
// gemm v3: 64x256 tile, KS=8, grid (64,8)=512 blocks, 80 KB LDS, 2 blocks/CU.
// 16 MFMA/wave/iter vs 8 B-DMAs; double-buffered; counted vmcnt(4) keeps the
// 4 A-prefetch loads in flight across the barrier; B-DMA issued 1 tile ahead
// with a 4x-longer compute phase to hide under.
// Per-iter issue order: [B(t+1) x8][A(t+2) x4] -> wait vmcnt(4) drains B only.
// ---------------------------------------------------------------------------
__global__ __launch_bounds__(256, 2) void gemm(const float* __restrict__ x,
                                               const unsigned short* __restrict__ cbsw,
                                               float* __restrict__ part,
                                               float* __restrict__ xxp) {
    __shared__ unsigned short As[2][8 * MT * 8];        // [p][q][row64][8]  2 x 8 KB
    __shared__ unsigned short Bs[2][8 * K_CODES * 8];   // [p][q][code][8]   2 x 32 KB
    const int t = threadIdx.x;
    const int lane = t & 63, w = t >> 6;
    const int h = lane >> 5, mr = lane & 31;
    const int m0 = blockIdx.x * MT;
    const int ks = blockIdx.y;
    const int k0 = ks * KSLICE;

    // A staging: thread t -> rows (t>>3) and (t>>3)+32, k-chunks acg and acg+32
    const int arow = t >> 3, acg = 4 * (t & 7);
    const float* ag = x + (size_t)(m0 + arow) * D_DIM + k0 + acg;
    const int aw0 = (((acg >> 3)    ) * MT + arow) * 8 + (acg & 7);
    const int aw1 = (((acg >> 3) + 4) * MT + arow) * 8 + (acg & 7);
    // B DMA: linear in cbsw; per-iter stride = 64 k * 256 codes = 16384 ushort
    const unsigned short* bg = cbsw + (size_t)(ks * NITER) * 16384 + t * 8;

    f32x16 acc00, acc01, acc10, acc11;
#pragma unroll
    for (int i = 0; i < 16; ++i) { acc00[i] = 0.f; acc01[i] = 0.f; acc10[i] = 0.f; acc11[i] = 0.f; }
    float sq0 = 0.f, sq1 = 0.f;

    // ---- prologue ----
#pragma unroll
    for (int r = 0; r < 8; ++r)
        __builtin_amdgcn_global_load_lds(
            (const __attribute__((address_space(1))) void*)(bg + r * 2048),
            (__attribute__((address_space(3))) void*)(&Bs[0][(t + 256 * r) * 8]),
            16, 0, 0);
    // A(0) regs
    float4 p0 = *(const float4*)(ag);
    float4 p1 = *(const float4*)(ag + 32);
    float4 p2 = *(const float4*)(ag + 32 * D_DIM);
    float4 p3 = *(const float4*)(ag + 32 * D_DIM + 32);
    // A(1) regs (stay in flight across prologue barrier)
    float4 c0 = *(const float4*)(ag + BK);
    float4 c1 = *(const float4*)(ag + BK + 32);
    float4 c2 = *(const float4*)(ag + BK + 32 * D_DIM);
    float4 c3 = *(const float4*)(ag + BK + 32 * D_DIM + 32);
    {
        ushort4 h0, h1, h2, h3;
        h0.x = f2bf(p0.x); h0.y = f2bf(p0.y); h0.z = f2bf(p0.z); h0.w = f2bf(p0.w);
        h1.x = f2bf(p1.x); h1.y = f2bf(p1.y); h1.z = f2bf(p1.z); h1.w = f2bf(p1.w);
        h2.x = f2bf(p2.x); h2.y = f2bf(p2.y); h2.z = f2bf(p2.z); h2.w = f2bf(p2.w);
        h3.x = f2bf(p3.x); h3.y = f2bf(p3.y); h3.z = f2bf(p3.z); h3.w = f2bf(p3.w);
        *(ushort4*)&As[0][aw0]       = h0;
        *(ushort4*)&As[0][aw1]       = h1;
        *(ushort4*)&As[0][aw0 + 256] = h2;   // row+32: +32*8 ushorts
        *(ushort4*)&As[0][aw1 + 256] = h3;
        sq0 += p0.x*p0.x + p0.y*p0.y + p0.z*p0.z + p0.w*p0.w
             + p1.x*p1.x + p1.y*p1.y + p1.z*p1.z + p1.w*p1.w;
        sq1 += p2.x*p2.x + p2.y*p2.y + p2.z*p2.z + p2.w*p2.w
             + p3.x*p3.x + p3.y*p3.y + p3.z*p3.z + p3.w*p3.w;
    }
    asm volatile("s_waitcnt vmcnt(4) lgkmcnt(0)" ::: "memory");
    __builtin_amdgcn_s_barrier();
    __builtin_amdgcn_sched_barrier(0);

    // ---- main loop ----
#pragma unroll
    for (int it = 0; it < NITER; ++it) {
        const int p = it & 1, pn = p ^ 1;

        // phase 1+2: stage tile it+1 into buffer pn (B via DMA, A from regs)
        if (it + 1 < NITER) {
#pragma unroll
            for (int r = 0; r < 8; ++r)
                __builtin_amdgcn_global_load_lds(
                    (const __attribute__((address_space(1))) void*)(bg + (size_t)(it + 1) * 16384 + r * 2048),
                    (__attribute__((address_space(3))) void*)(&Bs[pn][(t + 256 * r) * 8]),
                    16, 0, 0);
            ushort4 h0, h1, h2, h3;
            h0.x = f2bf(c0.x); h0.y = f2bf(c0.y); h0.z = f2bf(c0.z); h0.w = f2bf(c0.w);
            h1.x = f2bf(c1.x); h1.y = f2bf(c1.y); h1.z = f2bf(c1.z); h1.w = f2bf(c1.w);
            h2.x = f2bf(c2.x); h2.y = f2bf(c2.y); h2.z = f2bf(c2.z); h2.w = f2bf(c2.w);
            h3.x = f2bf(c3.x); h3.y = f2bf(c3.y); h3.z = f2bf(c3.z); h3.w = f2bf(c3.w);
            *(ushort4*)&As[pn][aw0]       = h0;
            *(ushort4*)&As[pn][aw1]       = h1;
            *(ushort4*)&As[pn][aw0 + 256] = h2;
            *(ushort4*)&As[pn][aw1 + 256] = h3;
            sq0 += c0.x*c0.x + c0.y*c0.y + c0.z*c0.z + c0.w*c0.w
                 + c1.x*c1.x + c1.y*c1.y + c1.z*c1.z + c1.w*c1.w;
            sq1 += c2.x*c2.x + c2.y*c2.y + c2.z*c2.z + c2.w*c2.w
                 + c3.x*c3.x + c3.y*c3.y + c3.z*c3.z + c3.w*c3.w;
        }
        // phase 3: issue A(it+2) prefetch (clamped -> stable vmcnt count of 4)
        const int t2 = (it + 2 < NITER) ? (it + 2) * BK : 0;
        float4 n0 = *(const float4*)(ag + t2);
        float4 n1 = *(const float4*)(ag + t2 + 32);
        float4 n2 = *(const float4*)(ag + t2 + 32 * D_DIM);
        float4 n3 = *(const float4*)(ag + t2 + 32 * D_DIM + 32);

        // phase 4: MFMA on tile it (buffer p)
        __builtin_amdgcn_s_setprio(1);
#pragma unroll
        for (int s = 0; s < 4; ++s) {
            const int q = 2 * s + h;
            bf16x8 af0 = *(const bf16x8*)&As[p][(q * MT + mr) * 8];
            bf16x8 af1 = *(const bf16x8*)&As[p][(q * MT + 32 + mr) * 8];
            bf16x8 b0  = *(const bf16x8*)&Bs[p][(q * K_CODES + w * 64 + mr) * 8];
            bf16x8 b1  = *(const bf16x8*)&Bs[p][(q * K_CODES + w * 64 + 32 + mr) * 8];
            acc00 = __builtin_amdgcn_mfma_f32_32x32x16_bf16(af0, b0, acc00, 0, 0, 0);
            acc01 = __builtin_amdgcn_mfma_f32_32x32x16_bf16(af0, b1, acc01, 0, 0, 0);
            acc10 = __builtin_amdgcn_mfma_f32_32x32x16_bf16(af1, b0, acc10, 0, 0, 0);
            acc11 = __builtin_amdgcn_mfma_f32_32x32x16_bf16(af1, b1, acc11, 0, 0, 0);
        }
        __builtin_amdgcn_s_setprio(0);

        // phase 5: counted drain (B(t+1) only) + barrier
        asm volatile("s_waitcnt vmcnt(4) lgkmcnt(0)" ::: "memory");
        __builtin_amdgcn_s_barrier();
        __builtin_amdgcn_sched_barrier(0);

        c0 = n0; c1 = n1; c2 = n2; c3 = n3;
    }

    // xx partials: reduce over the 8 threads sharing a row (lanes t&7)
    sq0 += __shfl_xor(sq0, 1); sq0 += __shfl_xor(sq0, 2); sq0 += __shfl_xor(sq0, 4);
    sq1 += __shfl_xor(sq1, 1); sq1 += __shfl_xor(sq1, 2); sq1 += __shfl_xor(sq1, 4);
    if ((t & 7) == 0) {
        xxp[(size_t)ks * B_ROWS + m0 + arow]      = sq0;
        xxp[(size_t)ks * B_ROWS + m0 + arow + 32] = sq1;
    }

    float* dst = part + ((size_t)ks * B_ROWS + m0) * K_CODES + w * 64;
#pragma unroll
    for (int r = 0; r < 16; ++r) {
        const int rowit = (r & 3) + 8 * (r >> 2) + 4 * h;
        dst[(size_t)rowit * K_CODES + mr]              = acc00[r];
        dst[(size_t)rowit * K_CODES + 32 + mr]         = acc01[r];
        dst[(size_t)(rowit + 32) * K_CODES + mr]       = acc10[r];
        dst[(size_t)(rowit + 32) * K_CODES + 32 + mr]  = acc11[r];
    }
}

// ---------------------------------------------------------------------------
// finish: wave-per-row. d2 from partials (f64), butterfly max, margin
// candidates; single candidate -> done; else exact f64 refinement (rare).
// ---------------------------------------------------------------------------
__global__ __launch_bounds__(256) void finish(const float* __restrict__ x,
                                              const float* __restrict__ cb,
                                              const float* __restrict__ part,
                                              const double* __restrict__ cc,
                                              const float* __restrict__ xxp,
                                              float* __restrict__ out) {
    const int lane = threadIdx.x & 63;
    const int row = blockIdx.x * 4 + (threadIdx.x >> 6);

    double xx = 0.0;
#pragma unroll
    for (int s = 0; s < KS; ++s) xx += (double)xxp[(size_t)s * B_ROWS + row];
    float4 p[KS];
#pragma unroll
    for (int s = 0; s < KS; ++s)
        p[s] = ((const float4*)(part + ((size_t)s * B_ROWS + row) * K_CODES))[lane];
    double v[4];
    {
        double s0 = 0.0, s1 = 0.0, s2 = 0.0, s3 = 0.0;
#pragma unroll
        for (int s = 0; s < KS; ++s) {
            s0 += (double)p[s].x; s1 += (double)p[s].y;
            s2 += (double)p[s].z; s3 += (double)p[s].w;
        }
        v[0] = xx + cc[4 * lane + 0] - 2.0 * s0;
        v[1] = xx + cc[4 * lane + 1] - 2.0 * s1;
        v[2] = xx + cc[4 * lane + 2] - 2.0 * s2;
        v[3] = xx + cc[4 * lane + 3] - 2.0 * s3;
    }

    double mx = fmax(fmax(v[0], v[1]), fmax(v[2], v[3]));
    for (int off = 32; off; off >>= 1) mx = fmax(mx, __shfl_xor(mx, off));
    const double thr = mx - MARGIN;

    unsigned long long b[4];
#pragma unroll
    for (int j = 0; j < 4; ++j) b[j] = __ballot(v[j] >= thr);
    const int total = __popcll(b[0]) + __popcll(b[1]) + __popcll(b[2]) + __popcll(b[3]);

    int bestk = 0; double best;
    if (total == 1) {
        best = mx;   // lone candidate IS the max; error bound guarantees argmax
#pragma unroll
        for (int j = 0; j < 4; ++j)
            if (b[j]) bestk = 4 * (int)__builtin_ctzll(b[j]) + j;
    } else {
        const float4* xrow4 = (const float4*)(x + (size_t)row * D_DIM);
        int flags = 0;
#pragma unroll
        for (int j = 0; j < 4; ++j) if (v[j] >= thr) flags |= 1 << j;
        unsigned long long cand = __ballot(flags != 0);
        best = -1.0e300;
        while (cand) {
            const int lsrc = __builtin_ctzll(cand);
            cand &= cand - 1;
            const int f = __shfl(flags, lsrc);
            for (int j = 0; j < 4; ++j) {
                if (!((f >> j) & 1)) continue;
                const int k = 4 * lsrc + j;
                const float4* crow4 = (const float4*)(cb + (size_t)k * D_DIM);
                double a0 = 0.0, a1 = 0.0, a2 = 0.0, a3 = 0.0;
#pragma unroll
                for (int i = 0; i < 16; ++i) {
                    float4 xa = xrow4[i * 64 + lane];
                    float4 ca = crow4[i * 64 + lane];
                    a0 += (double)xa.x * ca.x; a1 += (double)xa.y * ca.y;
                    a2 += (double)xa.z * ca.z; a3 += (double)xa.w * ca.w;
                }
                double s = (a0 + a1) + (a2 + a3);
                for (int off = 32; off; off >>= 1) s += __shfl_xor(s, off);
                const double d2e = xx + cc[k] - 2.0 * s;    // identical across lanes
                if (d2e > best) { best = d2e; bestk = k; }  // ascending k, strict >
            }
        }
    }

    if (lane == 0) {
        out[IDX_OFF + row]  = (float)bestk;
        out[LOSS_OFF + row] = (float)(1.25 * best / (double)D_DIM);
    }
    float4 z = make_float4(0.f, 0.f, 0.f, 0.f);
    ((float4*)(out + PROBS_OFF + (size_t)row * K_CODES))[lane] = z;
    const float4* src = (const float4*)(cb + (size_t)bestk * D_DIM);
    float4* dst = (float4*)(out + (size_t)row * D_DIM);
#pragma unroll
    for (int i = 0; i < 16; ++i) dst[i * 64 + lane] = src[i * 64 + lane];
}

// ---------------------------------------------------------------------------
extern "C" void kernel_launch(void* const* d_in, const int* in_sizes, int n_in,
                              void* d_out, int out_size, void* d_ws, size_t ws_size,
                              hipStream_t stream) {
    const float* x  = (const float*)d_in[0];
    const float* cb = (const float*)d_in[1];
    float* out = (float*)d_out;

    float*          part = (float*)d_ws;
    unsigned short* cbsw = (unsigned short*)((char*)d_ws + PART_ELEMS * sizeof(float));
    double*         cc   = (double*)((char*)cbsw + (size_t)K_CODES * D_DIM * sizeof(unsigned short));
    float*          xxp  = (float*)(cc + K_CODES);

    hipLaunchKernelGGL(prep_cb, dim3(256),     dim3(64),  0, stream, cb, cbsw, cc);
    hipLaunchKernelGGL(gemm,    dim3(64, KS),  dim3(256), 0, stream, x, cbsw, part, xxp);
    hipLaunchKernelGGL(finish,  dim3(1024),    dim3(256), 0, stream, x, cb, part, cc, xxp, out);
}